// Round 4
// baseline (33.167 us; speedup 1.0000x reference)
//
#include <hip/hip_runtime.h>
#include <math.h>

#define NQ   10
#define NL   4
#define NREG 8    // 1024 amplitudes / (2 waves * 64 lanes)

typedef float f32x2 __attribute__((ext_vector_type(2)));

// ---------------------------------------------------------------------------
// Compile-time GF(2) tracking of the CNOT rings.
// Invariant: stored[q] = amp[L q]. Gate on logical bit p pairs stored indices
// {q, q ^ m}, m = column p of L^-1; logical bit value at q = parity(row_p(L)&q).
// CNOT rings only update L / L^-1 (no data movement).
// Layer-3 pruning: observable sign(q) = parity(sgn & q), sgn = final L[0];
// a layer-3 gate with parity(sgn & m)==0 commutes with the measurement -> drop.
// Physical q bits: [5:0]=lane, [8:6]=reg, [9]=wave. Gates with m bit 9 set are
// cross-wave: exchanged via LDS (xpar = which of 2 LDS buffers to use).
// ---------------------------------------------------------------------------
struct MaskTab {
    int m[NL * NQ]; int d[NL * NQ]; bool keep[NL * NQ]; int xpar[NL * NQ];
    int sgn; bool ok;
};

constexpr MaskTab make_masks() {
    MaskTab t{};
    int L[NQ] = {}, Li[NQ] = {};
    for (int p = 0; p < NQ; ++p) { L[p] = 1 << p; Li[p] = 1 << p; }
    for (int l = 0; l < NL; ++l) {
        for (int w = 0; w < NQ; ++w) {
            int p = NQ - 1 - w;
            int mm = 0;
            for (int tt = 0; tt < NQ; ++tt) mm |= ((Li[tt] >> p) & 1) << tt; // col p of L^-1
            t.m[l * NQ + w] = mm;
            t.d[l * NQ + w] = L[p];                                          // row p of L
        }
        int r = (l % (NQ - 1)) + 1;
        for (int w = 0; w < NQ; ++w) {           // L <- P_l^-1 L
            int pc = NQ - 1 - w;
            int tq = w + r; if (tq >= NQ) tq -= NQ;
            int pt = NQ - 1 - tq;
            L[pt] ^= L[pc];
        }
        for (int w = 0; w < NQ; ++w) {           // Li <- Li P_l
            int pc = NQ - 1 - w;
            int tq = w + r; if (tq >= NQ) tq -= NQ;
            int pt = NQ - 1 - tq;
            for (int p = 0; p < NQ; ++p)
                Li[p] ^= ((Li[p] >> pt) & 1) << pc;
        }
    }
    t.sgn = L[0];
    for (int gi = 0; gi < NL * NQ; ++gi) {
        if (gi < (NL - 1) * NQ) { t.keep[gi] = true; continue; }
        t.keep[gi] = (__builtin_popcount((unsigned)(t.sgn & t.m[gi])) & 1) != 0;
    }
    int cnt = 0;
    for (int gi = 0; gi < NL * NQ; ++gi) {
        t.xpar[gi] = 0;
        if (t.keep[gi] && ((t.m[gi] >> 9) & 1)) { t.xpar[gi] = cnt & 1; ++cnt; }
    }
    bool ok = true; // verify L * Li == I
    for (int p = 0; p < NQ; ++p) {
        int row = 0;
        for (int k = 0; k < NQ; ++k)
            if ((L[p] >> k) & 1) row ^= Li[k];
        if (row != (1 << p)) ok = false;
    }
    t.ok = ok;
    return t;
}

static constexpr MaskTab MK = make_masks();
static_assert(MK.ok, "GF(2) inverse check failed");

__device__ __forceinline__ float fxor(float a, unsigned s) {
    return __uint_as_float(__float_as_uint(a) ^ s);
}
__device__ __forceinline__ f32x2 bc2(float v) { f32x2 r; r.x = v; r.y = v; return r; }

// n = sc*s + pc*p with sc=(g00x, scy), pc=(pcx, g01y) sign-prefixed
// (Rot structure: g11 = conj(g00), g10 = -conj(g01)).
__device__ __forceinline__ f32x2 cmul2v(f32x2 s, f32x2 p,
                                        float g00x, float scy, float pcx, float g01y) {
    f32x2 sswap; sswap.x = -s.y; sswap.y = s.x;
    f32x2 pswap; pswap.x = -p.y; pswap.y = p.x;
    f32x2 n = s * bc2(g00x);
    n += sswap * bc2(scy);
    n += p * bc2(pcx);
    n += pswap * bc2(g01y);
    return n;
}

// ---------------------------------------------------------------------------
// One sample per 2-wave block (128 threads). 8 f32x2 regs/lane.
// Cross-wave gates exchange through double-buffered LDS, 1 barrier each.
// ---------------------------------------------------------------------------
__global__ __launch_bounds__(128) void qnn_kernel(const float* __restrict__ x,
                                                  const float* __restrict__ wts,
                                                  float* __restrict__ out) {
    __shared__ f32x2 xbuf[2][1024];     // 2 x 8KB double buffer
    __shared__ float partial[2];
    const int b    = blockIdx.x;
    const int tid  = threadIdx.x;
    const int W    = tid >> 6;          // wave id = q bit 9
    const int lane = tid & 63;

    // ---- gate coefficients: lane gi (<40) computes Rot gate gi (per wave,
    //      redundantly); broadcast later via __shfl(.., gi) -> readlane.
    float g00x_r = 0.f, g00y_r = 0.f, g01x_r = 0.f, g01y_r = 0.f;
    if (lane < NL * NQ) {
        float phi = wts[lane * 3 + 0];
        float th  = wts[lane * 3 + 1];
        float om  = wts[lane * 3 + 2];
        float st_, ct_; sincosf(0.5f * th, &st_, &ct_);
        float sp,  cp;  sincosf(0.5f * (phi + om), &sp, &cp);
        float sm,  cm;  sincosf(0.5f * (phi - om), &sm, &cm);
        g00x_r =  cp * ct_;  g00y_r = -sp * ct_;   // m00 = e^{-i(phi+om)/2} cos
        g01x_r = -cm * st_;  g01y_r = -sm * st_;   // m01 = -e^{+i(phi-om)/2} sin
    }

    // ---- RX encoding angles: lane w (<10) computes sincos(pi*x_w/2)
    float myc, mys;
    {
        int w = (lane < NQ) ? lane : 0;
        float ang = 0.5f * 3.14159265358979323846f * x[b * NQ + w];
        sincosf(ang, &mys, &myc);
    }
    float cpv[NQ], spv[NQ];              // indexed by bit position p = 9-w
    #pragma unroll
    for (int p = 0; p < NQ; ++p) {
        cpv[p] = __shfl(myc, NQ - 1 - p, 64);
        spv[p] = __shfl(mys, NQ - 1 - p, 64);
    }

    // ---- init: product state  a[q] = prod_p(bit? s:c) * (-i)^popc(q)
    float LP = (W ? spv[9] : cpv[9]);    // bit 9 = wave id
    #pragma unroll
    for (int p = 0; p < 6; ++p)
        LP *= ((lane >> p) & 1) ? spv[p] : cpv[p];
    const int kl = __popc(lane) + W;
    const int b0 = kl & 1, b1 = (kl >> 1) & 1;
    const float bx = b0 ? 0.f : (b1 ? -1.f : 1.f);    // (-i)^kl
    const float by = b0 ? (b1 ? 1.f : -1.f) : 0.f;
    const float phx[4] = { bx,  by, -bx, -by };       // (-i)^(kl+c)
    const float phy[4] = { by, -bx, -by,  bx };

    f32x2 st[NREG];
    #pragma unroll
    for (int j = 0; j < NREG; ++j) {
        float HP = LP;
        #pragma unroll
        for (int p = 6; p < 9; ++p)
            HP *= ((j >> (p - 6)) & 1) ? spv[p] : cpv[p];
        const int c = __popc(j) & 3;                  // compile-time
        st[j].x = HP * phx[c];
        st[j].y = HP * phy[c];
    }

    // ---- Rot gates in stored (permuted) space; CNOT rings are free.
    #pragma unroll
    for (int l = 0; l < NL; ++l) {
        #pragma unroll
        for (int w = 0; w < NQ; ++w) {
            const int gi = l * NQ + w;
            if (!MK.keep[gi]) continue;
            const int m     = MK.m[gi];
            const int d     = MK.d[gi];
            const int mW    = (m >> 9) & 1;
            const int mreg  = (m >> 6) & 7;
            const int mlane = m & 63;
            const int dW    = (d >> 9) & 1;
            const int dreg  = (d >> 6) & 7;
            const int dlane = d & 63;

            const float g00x = __shfl(g00x_r, gi, 64);
            const float g00y = __shfl(g00y_r, gi, 64);
            const float g01x = __shfl(g01x_r, gi, 64);
            const float g01y = __shfl(g01y_r, gi, 64);

            const int bl = (__popc(dlane & lane) ^ (dW & W)) & 1;  // lane+wave bit part
            const unsigned s0 = (unsigned)bl << 31;
            const float scy0 = fxor(g00y, s0), pcx0 = fxor(g01x, s0);
            const float scy1 = fxor(g00y, s0 ^ 0x80000000u), pcx1 = fxor(g01x, s0 ^ 0x80000000u);

            if (mW) {
                // ---- cross-wave gate: exchange through LDS (double-buffered)
                f32x2* bufk = xbuf[MK.xpar[gi]];
                #pragma unroll
                for (int j = 0; j < NREG; ++j)
                    bufk[(W << 9) | (j << 6) | lane] = st[j];
                __syncthreads();
                const int rbase = (W ^ 1) << 9;
                #pragma unroll
                for (int j = 0; j < NREG; ++j) {
                    f32x2 p = bufk[rbase | ((j ^ mreg) << 6) | (lane ^ mlane)];
                    const int v = __popc(dreg & j) & 1;            // compile-time
                    st[j] = cmul2v(st[j], p, g00x, v ? scy1 : scy0, v ? pcx1 : pcx0, g01y);
                }
            } else {
                #pragma unroll
                for (int j = 0; j < NREG; ++j) {
                    if (mreg == 0) {
                        f32x2 s = st[j];
                        f32x2 p = s;
                        p.x = __shfl_xor(p.x, mlane, 64);
                        p.y = __shfl_xor(p.y, mlane, 64);
                        const int v = __popc(dreg & j) & 1;        // compile-time
                        st[j] = cmul2v(s, p, g00x, v ? scy1 : scy0, v ? pcx1 : pcx0, g01y);
                    } else if (j < (j ^ mreg)) {                   // each pair once
                        const int j2 = j ^ mreg;
                        f32x2 sA = st[j], sB = st[j2];
                        f32x2 pA = sB,    pB = sA;
                        if (mlane) {
                            pA.x = __shfl_xor(pA.x, mlane, 64);
                            pA.y = __shfl_xor(pA.y, mlane, 64);
                            pB.x = __shfl_xor(pB.x, mlane, 64);
                            pB.y = __shfl_xor(pB.y, mlane, 64);
                        }
                        const int vA = __popc(dreg & j)  & 1;      // compile-time
                        const int vB = __popc(dreg & j2) & 1;
                        st[j]  = cmul2v(sA, pA, g00x, vA ? scy1 : scy0, vA ? pcx1 : pcx0, g01y);
                        st[j2] = cmul2v(sB, pB, g00x, vB ? scy1 : scy0, vB ? pcx1 : pcx0, g01y);
                    }
                }
            }
        }
    }

    // ---- <Z>: sign(q) = (-1)^parity(sgn & q)
    const int sl = (__popc(MK.sgn & 63 & lane) ^ (((MK.sgn >> 9) & 1) & W)) & 1;
    const float bsign = sl ? -1.f : 1.f;
    float acc = 0.f;
    #pragma unroll
    for (int j = 0; j < NREG; ++j) {
        float t = fmaf(st[j].x, st[j].x, st[j].y * st[j].y);
        const int cj = __popc(((MK.sgn >> 6) & 7) & j) & 1;        // compile-time
        acc = fmaf(t, cj ? -bsign : bsign, acc);
    }
    #pragma unroll
    for (int mm = 32; mm >= 1; mm >>= 1)
        acc += __shfl_xor(acc, mm, 64);
    if (lane == 0) partial[W] = acc;
    __syncthreads();
    if (tid == 0) out[b] = partial[0] + partial[1];
}

extern "C" void kernel_launch(void* const* d_in, const int* in_sizes, int n_in,
                              void* d_out, int out_size, void* d_ws, size_t ws_size,
                              hipStream_t stream) {
    (void)n_in; (void)d_ws; (void)ws_size; (void)out_size;
    const float* x   = (const float*)d_in[0];   // (2048, 10) float32
    const float* wts = (const float*)d_in[1];   // (4, 10, 3) float32
    float* out = (float*)d_out;                 // (2048, 1) float32
    int B = in_sizes[0] / NQ;                   // 2048
    qnn_kernel<<<B, 128, 0, stream>>>(x, wts, out);
}

// Round 5
// 25.212 us; speedup vs baseline: 1.3155x; 1.3155x over previous
//
#include <hip/hip_runtime.h>
#include <math.h>

#define NQ   10
#define NL   4
#define NREG 16   // 1024 amplitudes / 64 lanes

typedef float f32x2 __attribute__((ext_vector_type(2)));

// ---------------------------------------------------------------------------
// Compile-time GF(2) tracking of the CNOT rings.
// Invariant: stored[q] = amp[L q]. Gate on logical bit p pairs stored indices
// {q, q ^ m}, m = column p of L^-1; logical bit value at q = parity(row_p(L)&q).
// CNOT rings only update L / L^-1 (no data movement).
// Layer 0 is NOT in the gate loop: it acts on the product state and is folded
// into the init (u'_p = Rot_w . RX-factor). Gate loop runs layers 1..NL-1.
// Layer-3 pruning: observable sign(q) = parity(sgn & q), sgn = final L[0];
// a layer-3 gate with parity(sgn & m)==0 commutes with the measurement -> drop
// (basis-invariant: parity(sgn&m) is preserved under any GL(10,2) re-basis).
// ---------------------------------------------------------------------------
struct MaskTab { int m[NL * NQ]; int d[NL * NQ]; bool keep[NL * NQ]; int sgn; bool ok; };

constexpr MaskTab make_masks() {
    MaskTab t{};
    int L[NQ] = {}, Li[NQ] = {};
    for (int p = 0; p < NQ; ++p) { L[p] = 1 << p; Li[p] = 1 << p; }
    for (int l = 0; l < NL; ++l) {
        for (int w = 0; w < NQ; ++w) {
            int p = NQ - 1 - w;
            int mm = 0;
            for (int tt = 0; tt < NQ; ++tt) mm |= ((Li[tt] >> p) & 1) << tt; // col p of L^-1
            t.m[l * NQ + w] = mm;
            t.d[l * NQ + w] = L[p];                                          // row p of L
        }
        int r = (l % (NQ - 1)) + 1;
        for (int w = 0; w < NQ; ++w) {           // L <- P_l^-1 L
            int pc = NQ - 1 - w;
            int tq = w + r; if (tq >= NQ) tq -= NQ;
            int pt = NQ - 1 - tq;
            L[pt] ^= L[pc];
        }
        for (int w = 0; w < NQ; ++w) {           // Li <- Li P_l
            int pc = NQ - 1 - w;
            int tq = w + r; if (tq >= NQ) tq -= NQ;
            int pt = NQ - 1 - tq;
            for (int p = 0; p < NQ; ++p)
                Li[p] ^= ((Li[p] >> pt) & 1) << pc;
        }
    }
    t.sgn = L[0];   // <Z> on logical LSB, in stored-index space
    for (int gi = 0; gi < NL * NQ; ++gi) {
        if (gi < NQ) { t.keep[gi] = false; continue; }            // layer 0: folded into init
        if (gi < (NL - 1) * NQ) { t.keep[gi] = true; continue; }  // layers 1..2
        t.keep[gi] = (__builtin_popcount((unsigned)(t.sgn & t.m[gi])) & 1) != 0;
    }
    bool ok = true; // verify L * Li == I
    for (int p = 0; p < NQ; ++p) {
        int row = 0;
        for (int k = 0; k < NQ; ++k)
            if ((L[p] >> k) & 1) row ^= Li[k];
        if (row != (1 << p)) ok = false;
    }
    t.ok = ok;
    return t;
}

static constexpr MaskTab MK = make_masks();
static_assert(MK.ok, "GF(2) inverse check failed");

__device__ __forceinline__ float fxor(float a, unsigned s) {
    return __uint_as_float(__float_as_uint(a) ^ s);
}
__device__ __forceinline__ f32x2 bc2(float v) { f32x2 r; r.x = v; r.y = v; return r; }
__device__ __forceinline__ f32x2 cmul(f32x2 a, f32x2 b) {
    f32x2 r;
    r.x = a.x * b.x - a.y * b.y;
    r.y = a.x * b.y + a.y * b.x;
    return r;
}

// n = sc*s + pc*p with sc=(g00x, scy), pc=(pcx, g01y) sign-prefixed
// (Rot structure: g11 = conj(g00), g10 = -conj(g01)).
__device__ __forceinline__ f32x2 cmul2v(f32x2 s, f32x2 p,
                                        float g00x, float scy, float pcx, float g01y) {
    f32x2 sswap; sswap.x = -s.y; sswap.y = s.x;
    f32x2 pswap; pswap.x = -p.y; pswap.y = p.x;
    f32x2 n = s * bc2(g00x);
    n += sswap * bc2(scy);
    n += p * bc2(pcx);
    n += pswap * bc2(g01y);
    return n;
}

// ---------------------------------------------------------------------------
// One sample per wave. Whole state in 32 VGPRs. No LDS, no barriers.
// ---------------------------------------------------------------------------
__global__ __launch_bounds__(64) void qnn_kernel(const float* __restrict__ x,
                                                 const float* __restrict__ wts,
                                                 float* __restrict__ out) {
    const int b    = blockIdx.x;
    const int lane = threadIdx.x;

    // ---- gate coefficients: lane gi (<40) computes Rot gate gi; broadcast
    //      later via __shfl(.., gi) -> readlane.
    float g00x_r = 0.f, g00y_r = 0.f, g01x_r = 0.f, g01y_r = 0.f;
    if (lane < NL * NQ) {
        float phi = wts[lane * 3 + 0];
        float th  = wts[lane * 3 + 1];
        float om  = wts[lane * 3 + 2];
        float st_, ct_; sincosf(0.5f * th, &st_, &ct_);
        float sp,  cp;  sincosf(0.5f * (phi + om), &sp, &cp);
        float sm,  cm;  sincosf(0.5f * (phi - om), &sm, &cm);
        g00x_r =  cp * ct_;  g00y_r = -sp * ct_;   // m00 = e^{-i(phi+om)/2} cos
        g01x_r = -cm * st_;  g01y_r = -sm * st_;   // m01 = -e^{+i(phi-om)/2} sin
    }

    // ---- RX encoding angles: lane w (<10) computes sincos(pi*x_w/2)
    float myc, mys;
    {
        int w = (lane < NQ) ? lane : 0;
        float ang = 0.5f * 3.14159265358979323846f * x[b * NQ + w];
        sincosf(ang, &mys, &myc);
    }

    // ---- fold layer-0 Rot into the RX product factors (lane w holds wire w's
    //      gate since gi = 0*NQ+w = w):
    //      u0 = g00*cos + g01*(-i sin), u1 = -conj(g01)*cos + conj(g00)*(-i sin)
    float u0x_r = 0.f, u0y_r = 0.f, u1x_r = 0.f, u1y_r = 0.f;
    if (lane < NQ) {
        u0x_r =  g00x_r * myc + g01y_r * mys;
        u0y_r =  g00y_r * myc - g01x_r * mys;
        u1x_r = -g01x_r * myc - g00y_r * mys;
        u1y_r =  g01y_r * myc - g00x_r * mys;
    }
    // broadcast per-qubit factors; bit position p = 9-w -> lane 9-p
    f32x2 u0[NQ], u1[NQ];
    #pragma unroll
    for (int p = 0; p < NQ; ++p) {
        u0[p].x = __shfl(u0x_r, NQ - 1 - p, 64);
        u0[p].y = __shfl(u0y_r, NQ - 1 - p, 64);
        u1[p].x = __shfl(u1x_r, NQ - 1 - p, 64);
        u1[p].y = __shfl(u1y_r, NQ - 1 - p, 64);
    }

    // ---- init: product state after RX + layer-0 Rot:  a[q] = prod_p u'_{p,bit_p(q)}
    f32x2 PL = ((lane >> 0) & 1) ? u1[0] : u0[0];   // lane-part product, bits 0..5
    #pragma unroll
    for (int p = 1; p < 6; ++p)
        PL = cmul(PL, ((lane >> p) & 1) ? u1[p] : u0[p]);

    f32x2 t67[4], r89[4];
    #pragma unroll
    for (int a = 0; a < 4; ++a) {
        f32x2 r = cmul((a & 1) ? u1[6] : u0[6], (a & 2) ? u1[7] : u0[7]);
        t67[a] = cmul(PL, r);                        // fold lane product in
        r89[a] = cmul((a & 1) ? u1[8] : u0[8], (a & 2) ? u1[9] : u0[9]);
    }

    f32x2 st[NREG];
    #pragma unroll
    for (int j = 0; j < NREG; ++j)                   // j bits 0..3 = q bits 6..9
        st[j] = cmul(t67[j & 3], r89[j >> 2]);

    // ---- Rot gates (layers 1..3) in stored space; CNOT rings are free.
    //      Per gate: gather ALL partner values first (32 swizzles issue
    //      back-to-back, pipelined), then a pure-FMA compute pass.
    #pragma unroll
    for (int l = 1; l < NL; ++l) {
        #pragma unroll
        for (int w = 0; w < NQ; ++w) {
            const int gi = l * NQ + w;
            if (!MK.keep[gi]) continue;
            const int m     = MK.m[gi];
            const int d     = MK.d[gi];
            const int mreg  = (m >> 6) & 15;
            const int mlane = m & 63;
            const int dreg  = (d >> 6) & 15;
            const int dlane = d & 63;

            const float g00x = __shfl(g00x_r, gi, 64);
            const float g00y = __shfl(g00y_r, gi, 64);
            const float g01x = __shfl(g01x_r, gi, 64);
            const float g01y = __shfl(g01y_r, gi, 64);

            const int bl = __popc(dlane & lane) & 1;          // lane part of bit value
            const unsigned s0 = (unsigned)bl << 31;
            const float scy0 = fxor(g00y, s0), pcx0 = fxor(g01x, s0);
            const float scy1 = fxor(g00y, s0 ^ 0x80000000u), pcx1 = fxor(g01x, s0 ^ 0x80000000u);

            // gather phase: pt[j] = old st[j ^ mreg] from lane ^ mlane
            f32x2 pt[NREG];
            #pragma unroll
            for (int j = 0; j < NREG; ++j) {
                f32x2 p = st[j ^ mreg];
                if (mlane) {
                    p.x = __shfl_xor(p.x, mlane, 64);
                    p.y = __shfl_xor(p.y, mlane, 64);
                }
                pt[j] = p;
            }
            // compute phase: pure FMA
            #pragma unroll
            for (int j = 0; j < NREG; ++j) {
                const int v = __popc(dreg & j) & 1;            // compile-time
                st[j] = cmul2v(st[j], pt[j], g00x, v ? scy1 : scy0, v ? pcx1 : pcx0, g01y);
            }
        }
    }

    // ---- <Z>: sign(q) = (-1)^parity(sgn & q)
    const int sl = __popc(MK.sgn & 63 & lane) & 1;
    const float bsign = sl ? -1.f : 1.f;
    float acc = 0.f;
    #pragma unroll
    for (int j = 0; j < NREG; ++j) {
        float t = fmaf(st[j].x, st[j].x, st[j].y * st[j].y);
        const int cj = __popc(((MK.sgn >> 6) & 15) & j) & 1;   // compile-time
        acc = fmaf(t, cj ? -bsign : bsign, acc);
    }
    #pragma unroll
    for (int mm = 32; mm >= 1; mm >>= 1)
        acc += __shfl_xor(acc, mm, 64);
    if (lane == 0) out[b] = acc;
}

extern "C" void kernel_launch(void* const* d_in, const int* in_sizes, int n_in,
                              void* d_out, int out_size, void* d_ws, size_t ws_size,
                              hipStream_t stream) {
    (void)n_in; (void)d_ws; (void)ws_size; (void)out_size;
    const float* x   = (const float*)d_in[0];   // (2048, 10) float32
    const float* wts = (const float*)d_in[1];   // (4, 10, 3) float32
    float* out = (float*)d_out;                 // (2048, 1) float32
    int B = in_sizes[0] / NQ;                   // 2048
    qnn_kernel<<<B, 64, 0, stream>>>(x, wts, out);
}